// Round 6
// baseline (322.455 us; speedup 1.0000x reference)
//
#include <hip/hip_runtime.h>
#include <stdint.h>

#define M_DIM 4096
#define N_DIM 4096
#define K_DIM 4096
#define BM 128
#define BN 128
#define BKB 128   // K-bytes (= i8 elems) per tile

typedef __attribute__((ext_vector_type(4)))  int     int4v;   // 16 i8 A/B frag
typedef __attribute__((ext_vector_type(4)))  float   f32x4;
typedef __attribute__((ext_vector_type(8)))  uint8_t u8x8;

#define XSCALE (127.0f / 4.25f)
#define XDEQ   (4.25f / 127.0f)

// ---------------- fp32 -> i8 quantizers ----------------
__device__ __forceinline__ int8_t q8(float v) {
    float c = fminf(fmaxf(v * XSCALE, -127.0f), 127.0f);
    return (int8_t)(int)__builtin_rintf(c);
}
__device__ __forceinline__ int8_t s8(float v) {           // exact ternary sign
    return (int8_t)((v > 0.0f) - (v < 0.0f));
}

// ---------------- prep: cvt x, cvt W, zero-fill masked out, row compaction ----
// Block segments (uniform branch per block):
//   [0,8192)      cvt x   (8 elems/thread)
//   [8192,16384)  cvt W
//   [16384,32768) zero-fill: block z -> (row r=z>>2, tile t=z&3); if gate==0
//                 write 1024 zeros (disjoint from GEMM's writes: GEMM only
//                 touches gate==1 rows)
//   [32768,32832) compaction: unordered atomic append of gate==1 rows per tile
__global__ __launch_bounds__(256) void prep_kernel(
    const float* __restrict__ x, const float* __restrict__ w,
    const int* __restrict__ gate,
    int8_t* __restrict__ xq, int8_t* __restrict__ wq,
    float* __restrict__ out, int* __restrict__ list, int* __restrict__ cnt) {
    const int bz  = blockIdx.x;
    const int tid = threadIdx.x;
    u8x8 o;
    if (bz < 8192) {                       // ---- cvt x ----
        int idx = bz * 256 + tid;
        const f32x4* s = (const f32x4*)x;
        f32x4 a = s[idx * 2], b = s[idx * 2 + 1];
        o[0] = (uint8_t)q8(a[0]); o[1] = (uint8_t)q8(a[1]);
        o[2] = (uint8_t)q8(a[2]); o[3] = (uint8_t)q8(a[3]);
        o[4] = (uint8_t)q8(b[0]); o[5] = (uint8_t)q8(b[1]);
        o[6] = (uint8_t)q8(b[2]); o[7] = (uint8_t)q8(b[3]);
        *(u8x8*)(xq + (size_t)idx * 8) = o;
    } else if (bz < 16384) {               // ---- cvt W (sign) ----
        int idx = (bz - 8192) * 256 + tid;
        const f32x4* s = (const f32x4*)w;
        f32x4 a = s[idx * 2], b = s[idx * 2 + 1];
        o[0] = (uint8_t)s8(a[0]); o[1] = (uint8_t)s8(a[1]);
        o[2] = (uint8_t)s8(a[2]); o[3] = (uint8_t)s8(a[3]);
        o[4] = (uint8_t)s8(b[0]); o[5] = (uint8_t)s8(b[1]);
        o[6] = (uint8_t)s8(b[2]); o[7] = (uint8_t)s8(b[3]);
        *(u8x8*)(wq + (size_t)idx * 8) = o;
    } else if (bz < 32768) {               // ---- zero-fill masked tiles ----
        int z = bz - 16384;
        int r = z >> 2, t = z & 3;
        if (gate[r * 4 + t] != 0) return;
        f32x4 zero = {0.f, 0.f, 0.f, 0.f};
        *(f32x4*)(out + (size_t)r * N_DIM + t * 1024 + tid * 4) = zero;
    } else {                               // ---- compaction ----
        int u = (bz - 32768) * 256 + tid;  // 0..16383
        int t = u >> 12, r = u & 4095;     // wave-uniform t -> coalesced atomic
        if (gate[r * 4 + t] != 0) {
            int pos = atomicAdd(&cnt[t], 1);
            list[t * 4096 + pos] = r;
        }
    }
}

// ---------------- async global->LDS, 16B per lane ----------------
__device__ __forceinline__ void gload_lds16(const int8_t* g, int8_t* l) {
    __builtin_amdgcn_global_load_lds(
        (__attribute__((address_space(1))) void*)(g),
        (__attribute__((address_space(3))) void*)(l),
        16, 0, 0);
}

// ---------------- compacted i8 GEMM, 16x16x64 MFMA (verified geometry) ----
// grid: x = col-block (0..7 within tile), y = row-block (0..31), z = gate tile.
// A rows come from list[t][...]; blocks past count[t] exit. Partial blocks
// clamp to count-1 -> duplicate rows -> identical duplicate writes (benign).
__global__ __launch_bounds__(256, 2) void trix_gemm(
    const int8_t* __restrict__ A,        // xq i8 [4096][4096]
    const int8_t* __restrict__ B,        // wq i8 [4096][4096] (O-major, K contig)
    const int* __restrict__ list,        // [4][4096] compacted rows
    const int* __restrict__ cnt,         // [4]
    const float* __restrict__ scales,    // [4096]
    float* __restrict__ out)             // [4096][4096] fp32
{
    const int t     = blockIdx.z;
    const int count = cnt[t];
    const int rb    = blockIdx.y;
    if (rb * 128 >= count) return;

    __shared__ __align__(16) int8_t As[BM * BKB];   // 16 KB
    __shared__ __align__(16) int8_t Bs[BN * BKB];   // 16 KB
    __shared__ int ridx[128];

    const int tid  = threadIdx.x;
    if (tid < 128) {
        int i = rb * 128 + tid;
        ridx[tid] = list[t * 4096 + min(i, count - 1)];
    }
    __syncthreads();

    const int lane = tid & 63;
    const int wave = tid >> 6;       // 0..3
    const int wm   = wave >> 1;      // 0..1
    const int wn   = wave & 1;       // 0..1
    const int quad = lane >> 4;      // 0..3
    const int ln16 = lane & 15;

    const int n0 = t * 1024 + blockIdx.x * 128;

    // ---- staging: 4 issues each for A and B per K-tile (1 KB per issue) ----
    const int srow   = lane >> 3;              // 0..7
    const int gchunk = (lane & 7) ^ srow;      // XOR swizzle in GLOBAL address
    const int8_t* a_src[4];
    const int8_t* b_src[4];
    int8_t* a_dst[4];
    int8_t* b_dst[4];
#pragma unroll
    for (int j = 0; j < 4; ++j) {
        int cidx = j * 4 + wave;
        a_src[j] = A + (size_t)ridx[cidx * 8 + srow] * K_DIM + gchunk * 16;
        b_src[j] = B + (size_t)(n0 + cidx * 8 + srow) * K_DIM + gchunk * 16;
        a_dst[j] = As + cidx * 1024;   // 8 rows x 128 B; HW adds lane*16B
        b_dst[j] = Bs + cidx * 1024;
    }

    // ---- fragment read addresses: lane reads 16 i8 at row, chunk quad+4*kk ----
    const int8_t* a_rd[4][2];
    const int8_t* b_rd[4][2];
#pragma unroll
    for (int i = 0; i < 4; ++i) {
        int arow = wm * 64 + i * 16 + ln16;
        int brow = wn * 64 + i * 16 + ln16;
#pragma unroll
        for (int kk = 0; kk < 2; ++kk) {
            int ch = quad + 4 * kk;
            a_rd[i][kk] = As + arow * 128 + ((ch ^ (arow & 7)) * 16);
            b_rd[i][kk] = Bs + brow * 128 + ((ch ^ (brow & 7)) * 16);
        }
    }

    int4v acc[4][4];
#pragma unroll
    for (int i = 0; i < 4; ++i)
#pragma unroll
        for (int j = 0; j < 4; ++j)
            acc[i][j] = (int4v){0, 0, 0, 0};

    for (int kt = 0; kt < K_DIM; kt += BKB) {   // 32 tiles
#pragma unroll
        for (int j = 0; j < 4; ++j) {
            gload_lds16(a_src[j], a_dst[j]);
            gload_lds16(b_src[j], b_dst[j]);
        }
#pragma unroll
        for (int j = 0; j < 4; ++j) { a_src[j] += BKB; b_src[j] += BKB; }
        __syncthreads();

#pragma unroll
        for (int kk = 0; kk < 2; ++kk) {
            int4v af[4], bf[4];
#pragma unroll
            for (int i = 0; i < 4; ++i) af[i] = *(const int4v*)a_rd[i][kk];
#pragma unroll
            for (int i = 0; i < 4; ++i) bf[i] = *(const int4v*)b_rd[i][kk];
#pragma unroll
            for (int i = 0; i < 4; ++i)
#pragma unroll
                for (int j = 0; j < 4; ++j)
                    acc[i][j] = __builtin_amdgcn_mfma_i32_16x16x64_i8(
                        af[i], bf[j], acc[i][j], 0, 0, 0);
        }
        __syncthreads();
    }

    // ---- epilogue: out = acc_i32 * (4.25/127) * scales[n]; rows via ridx ----
    float sc[4];
#pragma unroll
    for (int j = 0; j < 4; ++j) sc[j] = scales[n0 + wn * 64 + j * 16 + ln16] * XDEQ;

#pragma unroll
    for (int i = 0; i < 4; ++i) {
        int lbase = wm * 64 + i * 16 + quad * 4;
#pragma unroll
        for (int r = 0; r < 4; ++r) {
            int row = ridx[lbase + r];
            float* orow = out + (size_t)row * N_DIM + n0 + wn * 64 + ln16;
#pragma unroll
            for (int j = 0; j < 4; ++j)
                orow[j * 16] = (float)acc[i][j][r] * sc[j];
        }
    }
}

extern "C" void kernel_launch(void* const* d_in, const int* in_sizes, int n_in,
                              void* d_out, int out_size, void* d_ws, size_t ws_size,
                              hipStream_t stream) {
    const float* x      = (const float*)d_in[0];   // [4096][4096]
    const int*   gate   = (const int*)d_in[1];     // [4096][4]
    const float* weight = (const float*)d_in[2];   // [4096][4096]
    const float* scales = (const float*)d_in[3];   // [4096]
    float* out = (float*)d_out;

    int8_t* xq  = (int8_t*)d_ws;                          // 16 MB i8 x
    int8_t* wq  = xq + (size_t)M_DIM * K_DIM;             // 16 MB i8 W
    int*    cnt = (int*)(wq + (size_t)M_DIM * K_DIM);     // 4 ints
    int*    list = cnt + 256;                             // 4 x 4096 ints (aligned)

    hipMemsetAsync(cnt, 0, 16, stream);

    // 8192 (cvt x) + 8192 (cvt W) + 16384 (zero-fill) + 64 (compaction)
    prep_kernel<<<32832, 256, 0, stream>>>(x, weight, gate, xq, wq, out, list, cnt);

    dim3 grid(8, 32, 4);   // col-blocks x row-blocks x gate-tiles
    trix_gemm<<<grid, 256, 0, stream>>>(xq, wq, list, cnt, scales, out);
}

// Round 7
// 233.883 us; speedup vs baseline: 1.3787x; 1.3787x over previous
//
#include <hip/hip_runtime.h>
#include <stdint.h>

#define M_DIM 4096
#define N_DIM 4096
#define K_DIM 4096
#define BM 128
#define BN 128
#define BKB 128   // K-bytes (= i8 elems) per tile

typedef __attribute__((ext_vector_type(4)))  int     int4v;   // 16 i8 A/B frag
typedef __attribute__((ext_vector_type(4)))  float   f32x4;
typedef __attribute__((ext_vector_type(8)))  uint8_t u8x8;

#define XSCALE (127.0f / 4.25f)
#define XDEQ   (4.25f / 127.0f)

// ---------------- fp32 -> i8 quantizers ----------------
__device__ __forceinline__ int8_t q8(float v) {
    float c = fminf(fmaxf(v * XSCALE, -127.0f), 127.0f);
    return (int8_t)(int)__builtin_rintf(c);
}
__device__ __forceinline__ int8_t s8(float v) {           // exact ternary sign
    return (int8_t)((v > 0.0f) - (v < 0.0f));
}

// ---------------- prep: cvt x, cvt W, zero-fill masked out, row compaction ----
// Block segments (uniform branch per block):
//   [0,8192)      cvt x   (8 elems/thread)
//   [8192,16384)  cvt W
//   [16384,32768) zero-fill masked (row,tile) output runs
//   [32768,32832) compaction: WAVE-AGGREGATED append (1 atomic/wave, not 1/lane
//                 — per-lane same-address atomicAdd returns serialized at L2
//                 and cost ~80 us in the previous round)
__global__ __launch_bounds__(256) void prep_kernel(
    const float* __restrict__ x, const float* __restrict__ w,
    const int* __restrict__ gate,
    int8_t* __restrict__ xq, int8_t* __restrict__ wq,
    float* __restrict__ out, int* __restrict__ list, int* __restrict__ cnt) {
    const int bz  = blockIdx.x;
    const int tid = threadIdx.x;
    u8x8 o;
    if (bz < 8192) {                       // ---- cvt x ----
        int idx = bz * 256 + tid;
        const f32x4* s = (const f32x4*)x;
        f32x4 a = s[idx * 2], b = s[idx * 2 + 1];
        o[0] = (uint8_t)q8(a[0]); o[1] = (uint8_t)q8(a[1]);
        o[2] = (uint8_t)q8(a[2]); o[3] = (uint8_t)q8(a[3]);
        o[4] = (uint8_t)q8(b[0]); o[5] = (uint8_t)q8(b[1]);
        o[6] = (uint8_t)q8(b[2]); o[7] = (uint8_t)q8(b[3]);
        *(u8x8*)(xq + (size_t)idx * 8) = o;
    } else if (bz < 16384) {               // ---- cvt W (sign) ----
        int idx = (bz - 8192) * 256 + tid;
        const f32x4* s = (const f32x4*)w;
        f32x4 a = s[idx * 2], b = s[idx * 2 + 1];
        o[0] = (uint8_t)s8(a[0]); o[1] = (uint8_t)s8(a[1]);
        o[2] = (uint8_t)s8(a[2]); o[3] = (uint8_t)s8(a[3]);
        o[4] = (uint8_t)s8(b[0]); o[5] = (uint8_t)s8(b[1]);
        o[6] = (uint8_t)s8(b[2]); o[7] = (uint8_t)s8(b[3]);
        *(u8x8*)(wq + (size_t)idx * 8) = o;
    } else if (bz < 32768) {               // ---- zero-fill masked tiles ----
        int z = bz - 16384;
        int r = z >> 2, t = z & 3;
        if (gate[r * 4 + t] != 0) return;
        f32x4 zero = {0.f, 0.f, 0.f, 0.f};
        *(f32x4*)(out + (size_t)r * N_DIM + t * 1024 + tid * 4) = zero;
    } else {                               // ---- compaction (wave-aggregated) ----
        int u = (bz - 32768) * 256 + tid;  // 0..16383
        int t = u >> 12, r = u & 4095;     // t uniform per block (and per wave)
        int lane = tid & 63;
        bool active = (gate[r * 4 + t] != 0);
        unsigned long long m = __ballot(active);
        int prefix = __popcll(m & ((1ull << lane) - 1ull));
        int total  = __popcll(m);
        int base = 0;
        if (lane == 0) base = atomicAdd(&cnt[t], total);
        base = __shfl(base, 0);            // broadcast wave base
        if (active) list[t * 4096 + base + prefix] = r;
    }
}

// ---------------- async global->LDS, 16B per lane ----------------
__device__ __forceinline__ void gload_lds16(const int8_t* g, int8_t* l) {
    __builtin_amdgcn_global_load_lds(
        (__attribute__((address_space(1))) void*)(g),
        (__attribute__((address_space(3))) void*)(l),
        16, 0, 0);
}

// ---------------- compacted i8 GEMM, 16x16x64 MFMA (verified geometry) ----
// grid: x = col-block (0..7 within tile), y = row-block (0..31), z = gate tile.
// A rows come from list[t][...]; blocks past count[t] exit. Partial blocks
// clamp to count-1 -> duplicate rows -> identical duplicate writes (benign).
__global__ __launch_bounds__(256, 2) void trix_gemm(
    const int8_t* __restrict__ A,        // xq i8 [4096][4096]
    const int8_t* __restrict__ B,        // wq i8 [4096][4096] (O-major, K contig)
    const int* __restrict__ list,        // [4][4096] compacted rows
    const int* __restrict__ cnt,         // [4]
    const float* __restrict__ scales,    // [4096]
    float* __restrict__ out)             // [4096][4096] fp32
{
    const int t     = blockIdx.z;
    const int count = cnt[t];
    const int rb    = blockIdx.y;
    if (rb * 128 >= count) return;

    __shared__ __align__(16) int8_t As[BM * BKB];   // 16 KB
    __shared__ __align__(16) int8_t Bs[BN * BKB];   // 16 KB
    __shared__ int ridx[128];

    const int tid  = threadIdx.x;
    if (tid < 128) {
        int i = rb * 128 + tid;
        ridx[tid] = list[t * 4096 + min(i, count - 1)];
    }
    __syncthreads();

    const int lane = tid & 63;
    const int wave = tid >> 6;       // 0..3
    const int wm   = wave >> 1;      // 0..1
    const int wn   = wave & 1;       // 0..1
    const int quad = lane >> 4;      // 0..3
    const int ln16 = lane & 15;

    const int n0 = t * 1024 + blockIdx.x * 128;

    // ---- staging: 4 issues each for A and B per K-tile (1 KB per issue) ----
    const int srow   = lane >> 3;              // 0..7
    const int gchunk = (lane & 7) ^ srow;      // XOR swizzle in GLOBAL address
    const int8_t* a_src[4];
    const int8_t* b_src[4];
    int8_t* a_dst[4];
    int8_t* b_dst[4];
#pragma unroll
    for (int j = 0; j < 4; ++j) {
        int cidx = j * 4 + wave;
        a_src[j] = A + (size_t)ridx[cidx * 8 + srow] * K_DIM + gchunk * 16;
        b_src[j] = B + (size_t)(n0 + cidx * 8 + srow) * K_DIM + gchunk * 16;
        a_dst[j] = As + cidx * 1024;   // 8 rows x 128 B; HW adds lane*16B
        b_dst[j] = Bs + cidx * 1024;
    }

    // ---- fragment read addresses: lane reads 16 i8 at row, chunk quad+4*kk ----
    const int8_t* a_rd[4][2];
    const int8_t* b_rd[4][2];
#pragma unroll
    for (int i = 0; i < 4; ++i) {
        int arow = wm * 64 + i * 16 + ln16;
        int brow = wn * 64 + i * 16 + ln16;
#pragma unroll
        for (int kk = 0; kk < 2; ++kk) {
            int ch = quad + 4 * kk;
            a_rd[i][kk] = As + arow * 128 + ((ch ^ (arow & 7)) * 16);
            b_rd[i][kk] = Bs + brow * 128 + ((ch ^ (brow & 7)) * 16);
        }
    }

    int4v acc[4][4];
#pragma unroll
    for (int i = 0; i < 4; ++i)
#pragma unroll
        for (int j = 0; j < 4; ++j)
            acc[i][j] = (int4v){0, 0, 0, 0};

    for (int kt = 0; kt < K_DIM; kt += BKB) {   // 32 tiles
#pragma unroll
        for (int j = 0; j < 4; ++j) {
            gload_lds16(a_src[j], a_dst[j]);
            gload_lds16(b_src[j], b_dst[j]);
        }
#pragma unroll
        for (int j = 0; j < 4; ++j) { a_src[j] += BKB; b_src[j] += BKB; }
        __syncthreads();

#pragma unroll
        for (int kk = 0; kk < 2; ++kk) {
            int4v af[4], bf[4];
#pragma unroll
            for (int i = 0; i < 4; ++i) af[i] = *(const int4v*)a_rd[i][kk];
#pragma unroll
            for (int i = 0; i < 4; ++i) bf[i] = *(const int4v*)b_rd[i][kk];
#pragma unroll
            for (int i = 0; i < 4; ++i)
#pragma unroll
                for (int j = 0; j < 4; ++j)
                    acc[i][j] = __builtin_amdgcn_mfma_i32_16x16x64_i8(
                        af[i], bf[j], acc[i][j], 0, 0, 0);
        }
        __syncthreads();
    }

    // ---- epilogue: out = acc_i32 * (4.25/127) * scales[n]; rows via ridx ----
    float sc[4];
#pragma unroll
    for (int j = 0; j < 4; ++j) sc[j] = scales[n0 + wn * 64 + j * 16 + ln16] * XDEQ;

#pragma unroll
    for (int i = 0; i < 4; ++i) {
        int lbase = wm * 64 + i * 16 + quad * 4;
#pragma unroll
        for (int r = 0; r < 4; ++r) {
            int row = ridx[lbase + r];
            float* orow = out + (size_t)row * N_DIM + n0 + wn * 64 + ln16;
#pragma unroll
            for (int j = 0; j < 4; ++j)
                orow[j * 16] = (float)acc[i][j][r] * sc[j];
        }
    }
}

extern "C" void kernel_launch(void* const* d_in, const int* in_sizes, int n_in,
                              void* d_out, int out_size, void* d_ws, size_t ws_size,
                              hipStream_t stream) {
    const float* x      = (const float*)d_in[0];   // [4096][4096]
    const int*   gate   = (const int*)d_in[1];     // [4096][4]
    const float* weight = (const float*)d_in[2];   // [4096][4096]
    const float* scales = (const float*)d_in[3];   // [4096]
    float* out = (float*)d_out;

    int8_t* xq  = (int8_t*)d_ws;                          // 16 MB i8 x
    int8_t* wq  = xq + (size_t)M_DIM * K_DIM;             // 16 MB i8 W
    int*    cnt = (int*)(wq + (size_t)M_DIM * K_DIM);     // 4 ints
    int*    list = cnt + 256;                             // 4 x 4096 ints (aligned)

    hipMemsetAsync(cnt, 0, 16, stream);

    // 8192 (cvt x) + 8192 (cvt W) + 16384 (zero-fill) + 64 (compaction)
    prep_kernel<<<32832, 256, 0, stream>>>(x, weight, gate, xq, wq, out, list, cnt);

    dim3 grid(8, 32, 4);   // col-blocks x row-blocks x gate-tiles
    trix_gemm<<<grid, 256, 0, stream>>>(xq, wq, list, cnt, scales, out);
}